// Round 1
// baseline (1239.657 us; speedup 1.0000x reference)
//
#include <hip/hip_runtime.h>

#define N_USER   100000
#define N_ITEM   150000
#define N_NODES  250000
#define N_HID    64
#define E_UI     1000000
#define E_S      1000000

// ---------------------------------------------------------------------------
// init: A = concat(user, item); out = same (ui_embs[0] term)
__global__ __launch_bounds__(256) void init_concat(const float* __restrict__ u,
                                                   const float* __restrict__ it,
                                                   float* __restrict__ A,
                                                   float* __restrict__ out) {
    int i = blockIdx.x * 256 + threadIdx.x;          // float4 index
    const int nu4 = N_USER * N_HID / 4;
    const int nt4 = N_NODES * N_HID / 4;
    if (i >= nt4) return;
    float4 v = (i < nu4) ? ((const float4*)u)[i] : ((const float4*)it)[i - nu4];
    ((float4*)A)[i]   = v;
    ((float4*)out)[i] = v;
}

// copy src into two destinations (social init)
__global__ __launch_bounds__(256) void copy2(const float* __restrict__ src,
                                             float* __restrict__ d0,
                                             float* __restrict__ d1, int n4) {
    int i = blockIdx.x * 256 + threadIdx.x;
    if (i >= n4) return;
    float4 v = ((const float4*)src)[i];
    ((float4*)d0)[i] = v;
    ((float4*)d1)[i] = v;
}

// ---------------------------------------------------------------------------
// Y[row] = X[row] @ W   (W is 64x64 row-major, staged in LDS; one thread/row)
__global__ __launch_bounds__(256) void gemm64(const float* __restrict__ X,
                                              const float* __restrict__ W,
                                              float* __restrict__ Y, int nrows) {
    __shared__ float Ws[N_HID * N_HID];
    int tid = threadIdx.x;
#pragma unroll
    for (int c = 0; c < 16; ++c)                      // 4096 floats / 256 thr
        Ws[c * 256 + tid] = W[c * 256 + tid];
    __syncthreads();

    int row = blockIdx.x * 256 + tid;
    if (row >= nrows) return;

    float x[N_HID];
    const float4* xr = (const float4*)(X + (size_t)row * N_HID);
#pragma unroll
    for (int c = 0; c < 16; ++c) {
        float4 v = xr[c];
        x[4*c+0] = v.x; x[4*c+1] = v.y; x[4*c+2] = v.z; x[4*c+3] = v.w;
    }

    float4* yr = (float4*)(Y + (size_t)row * N_HID);
    for (int jc = 0; jc < 16; ++jc) {                 // 4 outputs at a time
        float4 acc = make_float4(0.f, 0.f, 0.f, 0.f);
#pragma unroll
        for (int k = 0; k < N_HID; ++k) {
            float4 w = *((const float4*)&Ws[k * N_HID + jc * 4]);
            acc.x += x[k] * w.x;
            acc.y += x[k] * w.y;
            acc.z += x[k] * w.z;
            acc.w += x[k] * w.w;
        }
        yr[jc] = acc;
    }
}

// ---------------------------------------------------------------------------
// scatter: Y[rows[e]] += vals[e] * X[cols[e]]   (one wave per edge, lane=h)
__global__ __launch_bounds__(256) void spmm_scatter(const int* __restrict__ rows,
                                                    const int* __restrict__ cols,
                                                    const float* __restrict__ vals,
                                                    const float* __restrict__ X,
                                                    float* __restrict__ Y,
                                                    int nedges) {
    long long t = (long long)blockIdx.x * 256 + threadIdx.x;
    int e = (int)(t >> 6);
    int h = (int)(t & 63);
    if (e >= nedges) return;
    int r = rows[e];
    int c = cols[e];
    float v = vals[e];
    atomicAdd(&Y[r * N_HID + h], v * X[c * N_HID + h]);
}

// ---------------------------------------------------------------------------
// leaky in-place (propagated state) + L2-normalized accumulate into out
__global__ __launch_bounds__(256) void leaky_norm_acc(float* __restrict__ Y,
                                                      float* __restrict__ out,
                                                      int nrows) {
    int row = blockIdx.x * 4 + (threadIdx.x >> 6);
    int h   = threadIdx.x & 63;
    if (row >= nrows) return;
    int idx = row * N_HID + h;
    float v = Y[idx];
    v = (v >= 0.f) ? v : 0.5f * v;
    Y[idx] = v;                       // next layer consumes unnormalized leaky
    float s = v * v;
#pragma unroll
    for (int off = 32; off > 0; off >>= 1) s += __shfl_xor(s, off, 64);
    float n = sqrtf(s);
    float scale = 1.f / fmaxf(n, 1e-12f);
    out[idx] += v * scale;
}

// ---------------------------------------------------------------------------
extern "C" void kernel_launch(void* const* d_in, const int* in_sizes, int n_in,
                              void* d_out, int out_size, void* d_ws, size_t ws_size,
                              hipStream_t stream) {
    const float* user_emb = (const float*)d_in[0];
    const float* item_emb = (const float*)d_in[1];
    const float* ui_w     = (const float*)d_in[2];   // 2 x 64 x 64
    const float* s_w      = (const float*)d_in[3];   // 2 x 64 x 64
    const int*   ui_rows  = (const int*)d_in[4];
    const int*   ui_cols  = (const int*)d_in[5];
    const float* ui_vals  = (const float*)d_in[6];
    const int*   s_rows   = (const int*)d_in[7];
    const int*   s_cols   = (const int*)d_in[8];
    const float* s_vals   = (const float*)d_in[9];

    float* out_ui = (float*)d_out;                           // 250000 x 64
    float* out_s  = (float*)d_out + (size_t)N_NODES * N_HID; // 100000 x 64

    const size_t bufBytes = (size_t)N_NODES * N_HID * sizeof(float); // 64 MB
    float* A = (float*)d_ws;
    float* B = (float*)((char*)d_ws + bufBytes);

    // ---------------- UI branch ----------------
    init_concat<<<(N_NODES * N_HID / 4 + 255) / 256, 256, 0, stream>>>(
        user_emb, item_emb, A, out_ui);

    for (int l = 0; l < 2; ++l) {
        gemm64<<<(N_NODES + 255) / 256, 256, 0, stream>>>(
            A, ui_w + l * N_HID * N_HID, B, N_NODES);
        hipMemsetAsync(A, 0, bufBytes, stream);
        spmm_scatter<<<(int)(((long long)E_UI * 64) / 256), 256, 0, stream>>>(
            ui_rows, ui_cols, ui_vals, B, A, E_UI);
        leaky_norm_acc<<<(N_NODES + 3) / 4, 256, 0, stream>>>(A, out_ui, N_NODES);
    }

    // ---------------- social branch ----------------
    copy2<<<(N_USER * N_HID / 4 + 255) / 256, 256, 0, stream>>>(
        user_emb, A, out_s, N_USER * N_HID / 4);

    const size_t sBytes = (size_t)N_USER * N_HID * sizeof(float);
    for (int l = 0; l < 2; ++l) {
        gemm64<<<(N_USER + 255) / 256, 256, 0, stream>>>(
            A, s_w + l * N_HID * N_HID, B, N_USER);
        hipMemsetAsync(A, 0, sBytes, stream);
        spmm_scatter<<<(int)(((long long)E_S * 64) / 256), 256, 0, stream>>>(
            s_rows, s_cols, s_vals, B, A, E_S);
        leaky_norm_acc<<<(N_USER + 3) / 4, 256, 0, stream>>>(A, out_s, N_USER);
    }
}

// Round 2
// 901.833 us; speedup vs baseline: 1.3746x; 1.3746x over previous
//
#include <hip/hip_runtime.h>

#define N_USER   100000
#define N_ITEM   150000
#define N_NODES  250000
#define N_HID    64
#define E_UI     1000000
#define E_S      1000000

// ===========================================================================
// Sorting (counting sort by destination row)
// ===========================================================================
__global__ __launch_bounds__(256) void edge_hist(const int* __restrict__ rows,
                                                 int* __restrict__ counts, int ne) {
    int i = blockIdx.x * 256 + threadIdx.x;
    if (i < ne) atomicAdd(&counts[rows[i]], 1);
}

// in-place exclusive scan per 256-block; block totals to blockSums
__global__ __launch_bounds__(256) void scan_block(int* __restrict__ rowStart,
                                                  int* __restrict__ blockSums, int n) {
    __shared__ int sm[256];
    int i = blockIdx.x * 256 + threadIdx.x;
    int v = (i < n) ? rowStart[i] : 0;
    sm[threadIdx.x] = v;
    __syncthreads();
    for (int off = 1; off < 256; off <<= 1) {
        int t = (threadIdx.x >= off) ? sm[threadIdx.x - off] : 0;
        __syncthreads();
        sm[threadIdx.x] += t;
        __syncthreads();
    }
    if (i < n) rowStart[i] = sm[threadIdx.x] - v;          // exclusive
    if (threadIdx.x == 255) blockSums[blockIdx.x] = sm[255];
}

__global__ __launch_bounds__(1024) void scan_sums(int* __restrict__ blockSums, int nb) {
    __shared__ int sm[1024];
    int v = (threadIdx.x < nb) ? blockSums[threadIdx.x] : 0;
    sm[threadIdx.x] = v;
    __syncthreads();
    for (int off = 1; off < 1024; off <<= 1) {
        int t = (threadIdx.x >= off) ? sm[threadIdx.x - off] : 0;
        __syncthreads();
        sm[threadIdx.x] += t;
        __syncthreads();
    }
    if (threadIdx.x < nb) blockSums[threadIdx.x] = sm[threadIdx.x] - v;  // exclusive
}

__global__ __launch_bounds__(256) void scan_add(int* __restrict__ rowStart,
                                                int* __restrict__ rowCur,
                                                const int* __restrict__ blockSums,
                                                int n, int ne) {
    int i = blockIdx.x * 256 + threadIdx.x;
    if (i < n) {
        int s = rowStart[i] + blockSums[blockIdx.x];
        rowStart[i] = s;
        rowCur[i] = s;
    }
    if (i == 0) rowStart[n] = ne;    // sentinel
}

__global__ __launch_bounds__(256) void edge_scatter(const int* __restrict__ rows,
                                                    const int* __restrict__ cols,
                                                    const float* __restrict__ vals,
                                                    int* __restrict__ rowCur,
                                                    unsigned long long* __restrict__ pairs,
                                                    int ne) {
    int i = blockIdx.x * 256 + threadIdx.x;
    if (i >= ne) return;
    int pos = atomicAdd(&rowCur[rows[i]], 1);
    unsigned long long p = (unsigned long long)(unsigned)cols[i] |
                           ((unsigned long long)__float_as_uint(vals[i]) << 32);
    pairs[pos] = p;
}

// ===========================================================================
// GEMM: Y[row] = X[row] @ W  (one thread per row, W in LDS)
// ===========================================================================
__device__ __forceinline__ void gemm_row(const float* __restrict__ Ws,
                                         const float* x, float* __restrict__ yr) {
    float4* y4 = (float4*)yr;
    for (int jc = 0; jc < 16; ++jc) {
        float4 acc = make_float4(0.f, 0.f, 0.f, 0.f);
#pragma unroll
        for (int k = 0; k < N_HID; ++k) {
            float4 w = *((const float4*)&Ws[k * N_HID + jc * 4]);
            acc.x += x[k] * w.x;
            acc.y += x[k] * w.y;
            acc.z += x[k] * w.z;
            acc.w += x[k] * w.w;
        }
        y4[jc] = acc;
    }
}

// layer-1 gemm: reads concat(src0,src1) row, writes out=x (embs[0]), B = x@W
__global__ __launch_bounds__(256) void gemm_init(const float* __restrict__ src0,
                                                 const float* __restrict__ src1, int n0,
                                                 const float* __restrict__ W,
                                                 float* __restrict__ B,
                                                 float* __restrict__ out, int nrows) {
    __shared__ float Ws[N_HID * N_HID];
    int tid = threadIdx.x;
#pragma unroll
    for (int c = 0; c < 16; ++c) Ws[c * 256 + tid] = W[c * 256 + tid];
    __syncthreads();

    int row = blockIdx.x * 256 + tid;
    if (row >= nrows) return;
    const float4* xr = (row < n0) ? (const float4*)(src0 + (size_t)row * N_HID)
                                  : (const float4*)(src1 + (size_t)(row - n0) * N_HID);
    float x[N_HID];
    float4* o4 = (float4*)(out + (size_t)row * N_HID);
#pragma unroll
    for (int c = 0; c < 16; ++c) {
        float4 v = xr[c];
        o4[c] = v;
        x[4*c+0] = v.x; x[4*c+1] = v.y; x[4*c+2] = v.z; x[4*c+3] = v.w;
    }
    gemm_row(Ws, x, B + (size_t)row * N_HID);
}

// mid-layer gemm: B = A@W
__global__ __launch_bounds__(256) void gemm64(const float* __restrict__ X,
                                              const float* __restrict__ W,
                                              float* __restrict__ Y, int nrows) {
    __shared__ float Ws[N_HID * N_HID];
    int tid = threadIdx.x;
#pragma unroll
    for (int c = 0; c < 16; ++c) Ws[c * 256 + tid] = W[c * 256 + tid];
    __syncthreads();

    int row = blockIdx.x * 256 + tid;
    if (row >= nrows) return;
    float x[N_HID];
    const float4* xr = (const float4*)(X + (size_t)row * N_HID);
#pragma unroll
    for (int c = 0; c < 16; ++c) {
        float4 v = xr[c];
        x[4*c+0] = v.x; x[4*c+1] = v.y; x[4*c+2] = v.z; x[4*c+3] = v.w;
    }
    gemm_row(Ws, x, Y + (size_t)row * N_HID);
}

// ===========================================================================
// Segmented SPMM + leaky + L2-norm-accumulate (one wave per destination row)
// ===========================================================================
__global__ __launch_bounds__(256) void spmm_fused(const unsigned long long* __restrict__ pairs,
                                                  const int* __restrict__ rowStart,
                                                  const float* __restrict__ X,
                                                  float* __restrict__ A,
                                                  float* __restrict__ out, int nrows) {
    int row = blockIdx.x * 4 + (threadIdx.x >> 6);
    int h   = threadIdx.x & 63;
    if (row >= nrows) return;
    int s = rowStart[row];
    int e = rowStart[row + 1];
    float acc = 0.f;
    for (int j = s; j < e; ++j) {
        unsigned long long p = pairs[j];                   // wave-uniform → broadcast
        int   c = (int)(p & 0xffffffffull);
        float v = __uint_as_float((unsigned)(p >> 32));
        acc += v * X[(size_t)c * N_HID + h];
    }
    float lv = (acc >= 0.f) ? acc : 0.5f * acc;
    size_t idx = (size_t)row * N_HID + h;
    A[idx] = lv;                                           // next layer's input
    float ss = lv * lv;
#pragma unroll
    for (int off = 32; off > 0; off >>= 1) ss += __shfl_xor(ss, off, 64);
    float inv = 1.f / fmaxf(sqrtf(ss), 1e-12f);
    out[idx] += lv * inv;
}

// ===========================================================================
// Fallback (R0 path) kernels — used only if ws_size is too small for sorting
// ===========================================================================
__global__ __launch_bounds__(256) void init_concat(const float* __restrict__ u,
                                                   const float* __restrict__ it,
                                                   float* __restrict__ A,
                                                   float* __restrict__ out) {
    int i = blockIdx.x * 256 + threadIdx.x;
    const int nu4 = N_USER * N_HID / 4;
    const int nt4 = N_NODES * N_HID / 4;
    if (i >= nt4) return;
    float4 v = (i < nu4) ? ((const float4*)u)[i] : ((const float4*)it)[i - nu4];
    ((float4*)A)[i]   = v;
    ((float4*)out)[i] = v;
}

__global__ __launch_bounds__(256) void copy2(const float* __restrict__ src,
                                             float* __restrict__ d0,
                                             float* __restrict__ d1, int n4) {
    int i = blockIdx.x * 256 + threadIdx.x;
    if (i >= n4) return;
    float4 v = ((const float4*)src)[i];
    ((float4*)d0)[i] = v;
    ((float4*)d1)[i] = v;
}

__global__ __launch_bounds__(256) void spmm_scatter(const int* __restrict__ rows,
                                                    const int* __restrict__ cols,
                                                    const float* __restrict__ vals,
                                                    const float* __restrict__ X,
                                                    float* __restrict__ Y, int nedges) {
    long long t = (long long)blockIdx.x * 256 + threadIdx.x;
    int e = (int)(t >> 6);
    int h = (int)(t & 63);
    if (e >= nedges) return;
    atomicAdd(&Y[rows[e] * N_HID + h], vals[e] * X[cols[e] * N_HID + h]);
}

__global__ __launch_bounds__(256) void leaky_norm_acc(float* __restrict__ Y,
                                                      float* __restrict__ out, int nrows) {
    int row = blockIdx.x * 4 + (threadIdx.x >> 6);
    int h   = threadIdx.x & 63;
    if (row >= nrows) return;
    int idx = row * N_HID + h;
    float v = Y[idx];
    v = (v >= 0.f) ? v : 0.5f * v;
    Y[idx] = v;
    float s = v * v;
#pragma unroll
    for (int off = 32; off > 0; off >>= 1) s += __shfl_xor(s, off, 64);
    out[idx] += v / fmaxf(sqrtf(s), 1e-12f);
}

// ===========================================================================
extern "C" void kernel_launch(void* const* d_in, const int* in_sizes, int n_in,
                              void* d_out, int out_size, void* d_ws, size_t ws_size,
                              hipStream_t stream) {
    const float* user_emb = (const float*)d_in[0];
    const float* item_emb = (const float*)d_in[1];
    const float* ui_w     = (const float*)d_in[2];
    const float* s_w      = (const float*)d_in[3];
    const int*   ui_rows  = (const int*)d_in[4];
    const int*   ui_cols  = (const int*)d_in[5];
    const float* ui_vals  = (const float*)d_in[6];
    const int*   s_rows   = (const int*)d_in[7];
    const int*   s_cols   = (const int*)d_in[8];
    const float* s_vals   = (const float*)d_in[9];

    float* out_ui = (float*)d_out;
    float* out_s  = (float*)d_out + (size_t)N_NODES * N_HID;

    const size_t bufBytes = (size_t)N_NODES * N_HID * sizeof(float);   // 64 MB
    float* A = (float*)d_ws;
    float* B = (float*)((char*)d_ws + bufBytes);

    const size_t pairsOff    = 2 * bufBytes;                 // 128,000,000
    const size_t rowStartOff = pairsOff + (size_t)E_UI * 8;  // +8,000,000
    const size_t rowCurOff   = rowStartOff + 1000448;        // (N_NODES+1)*4 padded
    const size_t sumsOff     = rowCurOff + 1000448;
    const size_t needBytes   = sumsOff + 8192;

    if (ws_size >= needBytes) {
        unsigned long long* pairs = (unsigned long long*)((char*)d_ws + pairsOff);
        int* rowStart  = (int*)((char*)d_ws + rowStartOff);
        int* rowCur    = (int*)((char*)d_ws + rowCurOff);
        int* blockSums = (int*)((char*)d_ws + sumsOff);

        for (int g = 0; g < 2; ++g) {
            const int   nrows = g == 0 ? N_NODES : N_USER;
            const int   ne    = g == 0 ? E_UI    : E_S;
            const int*  rws   = g == 0 ? ui_rows : s_rows;
            const int*  cls   = g == 0 ? ui_cols : s_cols;
            const float* vls  = g == 0 ? ui_vals : s_vals;
            const float* W    = g == 0 ? ui_w    : s_w;
            float* out        = g == 0 ? out_ui  : out_s;
            const int nb  = (nrows + 255) / 256;
            const int nbe = (ne + 255) / 256;

            // ---- sort edges by destination row ----
            hipMemsetAsync(rowStart, 0, (size_t)nrows * 4, stream);
            edge_hist<<<nbe, 256, 0, stream>>>(rws, rowStart, ne);
            scan_block<<<nb, 256, 0, stream>>>(rowStart, blockSums, nrows);
            scan_sums<<<1, 1024, 0, stream>>>(blockSums, nb);
            scan_add<<<nb, 256, 0, stream>>>(rowStart, rowCur, blockSums, nrows, ne);
            edge_scatter<<<nbe, 256, 0, stream>>>(rws, cls, vls, rowCur, pairs, ne);

            // ---- layer 1 ----
            gemm_init<<<nb, 256, 0, stream>>>(user_emb, item_emb, N_USER,
                                              W, B, out, nrows);
            spmm_fused<<<(nrows + 3) / 4, 256, 0, stream>>>(pairs, rowStart, B, A, out, nrows);
            // ---- layer 2 ----
            gemm64<<<nb, 256, 0, stream>>>(A, W + N_HID * N_HID, B, nrows);
            spmm_fused<<<(nrows + 3) / 4, 256, 0, stream>>>(pairs, rowStart, B, A, out, nrows);
        }
        return;
    }

    // ------------------- fallback: R0 atomic path -------------------
    init_concat<<<(N_NODES * N_HID / 4 + 255) / 256, 256, 0, stream>>>(
        user_emb, item_emb, A, out_ui);
    for (int l = 0; l < 2; ++l) {
        gemm64<<<(N_NODES + 255) / 256, 256, 0, stream>>>(
            A, ui_w + l * N_HID * N_HID, B, N_NODES);
        hipMemsetAsync(A, 0, bufBytes, stream);
        spmm_scatter<<<(int)(((long long)E_UI * 64) / 256), 256, 0, stream>>>(
            ui_rows, ui_cols, ui_vals, B, A, E_UI);
        leaky_norm_acc<<<(N_NODES + 3) / 4, 256, 0, stream>>>(A, out_ui, N_NODES);
    }
    copy2<<<(N_USER * N_HID / 4 + 255) / 256, 256, 0, stream>>>(
        user_emb, A, out_s, N_USER * N_HID / 4);
    const size_t sBytes = (size_t)N_USER * N_HID * sizeof(float);
    for (int l = 0; l < 2; ++l) {
        gemm64<<<(N_USER + 255) / 256, 256, 0, stream>>>(
            A, s_w + l * N_HID * N_HID, B, N_USER);
        hipMemsetAsync(A, 0, sBytes, stream);
        spmm_scatter<<<(int)(((long long)E_S * 64) / 256), 256, 0, stream>>>(
            s_rows, s_cols, s_vals, B, A, E_S);
        leaky_norm_acc<<<(N_USER + 3) / 4, 256, 0, stream>>>(A, out_s, N_USER);
    }
}

// Round 3
// 690.239 us; speedup vs baseline: 1.7960x; 1.3066x over previous
//
#include <hip/hip_runtime.h>

#define N_USER   100000
#define N_ITEM   150000
#define N_NODES  250000
#define N_HID    64
#define E_UI     1000000
#define E_S      1000000
#define N_TOT    (N_NODES + N_USER)      // 350000 histogram slots
#define E_TOT    (E_UI + E_S)            // 2000000

typedef unsigned long long ull;

// ===========================================================================
// Combined counting sort (both graphs, one pass)
// ===========================================================================
__global__ __launch_bounds__(256) void edge_hist2(const int* __restrict__ ui_rows,
                                                  const int* __restrict__ s_rows,
                                                  int* __restrict__ counts) {
    int i = blockIdx.x * 256 + threadIdx.x;
    if (i < E_UI)            atomicAdd(&counts[ui_rows[i]], 1);
    else if (i < E_TOT)      atomicAdd(&counts[N_NODES + s_rows[i - E_UI]], 1);
}

// exclusive scan, 512 elements per 256-thread block (Hillis–Steele in LDS)
__global__ __launch_bounds__(256) void scan_block512(int* __restrict__ data,
                                                     int* __restrict__ blockSums, int n) {
    __shared__ int sm[512];
    int t = threadIdx.x;
    int base = blockIdx.x * 512;
    int i0 = base + t, i1 = base + t + 256;
    int v0 = (i0 < n) ? data[i0] : 0;
    int v1 = (i1 < n) ? data[i1] : 0;
    sm[t] = v0; sm[t + 256] = v1;
    __syncthreads();
    for (int off = 1; off < 512; off <<= 1) {
        int a = (t >= off) ? sm[t - off] : 0;
        int b = (t + 256 >= off) ? sm[t + 256 - off] : 0;
        __syncthreads();
        sm[t] += a; sm[t + 256] += b;
        __syncthreads();
    }
    if (i0 < n) data[i0] = sm[t] - v0;           // exclusive
    if (i1 < n) data[i1] = sm[t + 256] - v1;
    if (t == 255) blockSums[blockIdx.x] = sm[511];
}

__global__ __launch_bounds__(1024) void scan_sums(int* __restrict__ blockSums, int nb) {
    __shared__ int sm[1024];
    int v = (threadIdx.x < nb) ? blockSums[threadIdx.x] : 0;
    sm[threadIdx.x] = v;
    __syncthreads();
    for (int off = 1; off < 1024; off <<= 1) {
        int t = (threadIdx.x >= off) ? sm[threadIdx.x - off] : 0;
        __syncthreads();
        sm[threadIdx.x] += t;
        __syncthreads();
    }
    if (threadIdx.x < nb) blockSums[threadIdx.x] = sm[threadIdx.x] - v;  // exclusive
}

__global__ __launch_bounds__(256) void scan_add512(int* __restrict__ data,
                                                   int* __restrict__ rowCur,
                                                   const int* __restrict__ blockSums,
                                                   int n, int total) {
    int base = blockIdx.x * 512;
    int s = blockSums[blockIdx.x];
#pragma unroll
    for (int k = 0; k < 2; ++k) {
        int i = base + threadIdx.x + k * 256;
        if (i < n) { int v = data[i] + s; data[i] = v; rowCur[i] = v; }
    }
    if (blockIdx.x == 0 && threadIdx.x == 0) data[n] = total;   // sentinel
}

__global__ __launch_bounds__(256) void edge_scatter2(const int* __restrict__ ui_rows,
                                                     const int* __restrict__ ui_cols,
                                                     const float* __restrict__ ui_vals,
                                                     const int* __restrict__ s_rows,
                                                     const int* __restrict__ s_cols,
                                                     const float* __restrict__ s_vals,
                                                     int* __restrict__ rowCur,
                                                     ull* __restrict__ pairs) {
    int i = blockIdx.x * 256 + threadIdx.x;
    int r, c; float v;
    if (i < E_UI)       { r = ui_rows[i];            c = ui_cols[i];       v = ui_vals[i]; }
    else if (i < E_TOT) { int k = i - E_UI;
                          r = N_NODES + s_rows[k];   c = s_cols[k];        v = s_vals[k]; }
    else return;
    int pos = atomicAdd(&rowCur[r], 1);
    pairs[pos] = (ull)(unsigned)c | ((ull)__float_as_uint(v) << 32);
}

// ===========================================================================
// gemm_init: wave per row-chunk, lane = column. out[row]=x ; B = x @ W
// ===========================================================================
__global__ __launch_bounds__(256) void gemm_init(const float* __restrict__ src0,
                                                 const float* __restrict__ src1, int n0,
                                                 const float* __restrict__ W,
                                                 float* __restrict__ B,
                                                 float* __restrict__ out,
                                                 int nrows, int rpw) {
    __shared__ float sm[4][N_HID];
    int wave = threadIdx.x >> 6;
    int h    = threadIdx.x & 63;
    float w[N_HID];
#pragma unroll
    for (int k = 0; k < N_HID; ++k) w[k] = W[k * N_HID + h];   // coalesced, L2-hot

    int row0 = (blockIdx.x * 4 + wave) * rpw;
    int row1 = min(row0 + rpw, nrows);
    for (int row = row0; row < row1; ++row) {
        const float* src = (row < n0) ? src0 + (size_t)row * N_HID
                                      : src1 + (size_t)(row - n0) * N_HID;
        float x = src[h];                         // coalesced
        size_t idx = (size_t)row * N_HID + h;
        out[idx] = x;                             // embs[0] term
        sm[wave][h] = x;
        asm volatile("s_waitcnt lgkmcnt(0)" ::: "memory");
        float bacc = 0.f;
#pragma unroll
        for (int k = 0; k < N_HID; k += 4) {
            float4 x4 = *(const float4*)&sm[wave][k];          // broadcast read
            bacc += x4.x * w[k] + x4.y * w[k+1] + x4.z * w[k+2] + x4.w * w[k+3];
        }
        B[idx] = bacc;
    }
}

// ===========================================================================
// spmm (+ leaky + l2norm-accum) ; FUSE: also next-layer GEMM epilogue
// ===========================================================================
template <bool FUSE>
__global__ __launch_bounds__(256) void spmm_fused2(const ull* __restrict__ pairs,
                                                   const int* __restrict__ rowStart,
                                                   const float* __restrict__ X,
                                                   const float* __restrict__ W,
                                                   float* __restrict__ Bout,
                                                   float* __restrict__ out,
                                                   int nrows, int rpw) {
    __shared__ float sm[4][N_HID];
    int wave = threadIdx.x >> 6;
    int h    = threadIdx.x & 63;
    float w[N_HID];
    if (FUSE) {
#pragma unroll
        for (int k = 0; k < N_HID; ++k) w[k] = W[k * N_HID + h];
    }
    int row0 = (blockIdx.x * 4 + wave) * rpw;
    if (row0 >= nrows) return;
    int row1 = min(row0 + rpw, nrows);
    int s = rowStart[row0];
    for (int row = row0; row < row1; ++row) {
        int e = rowStart[row + 1];
        float acc = 0.f;
        for (int j = s; j < e; j += 8) {          // batched: 8 gathers in flight
            int rem  = e - j;
            int last = e - 1;
            ull p0 = pairs[j];
            ull p1 = pairs[min(j + 1, last)];
            ull p2 = pairs[min(j + 2, last)];
            ull p3 = pairs[min(j + 3, last)];
            ull p4 = pairs[min(j + 4, last)];
            ull p5 = pairs[min(j + 5, last)];
            ull p6 = pairs[min(j + 6, last)];
            ull p7 = pairs[min(j + 7, last)];
            float g0 = X[(size_t)(unsigned)p0 * N_HID + h];
            float g1 = X[(size_t)(unsigned)p1 * N_HID + h];
            float g2 = X[(size_t)(unsigned)p2 * N_HID + h];
            float g3 = X[(size_t)(unsigned)p3 * N_HID + h];
            float g4 = X[(size_t)(unsigned)p4 * N_HID + h];
            float g5 = X[(size_t)(unsigned)p5 * N_HID + h];
            float g6 = X[(size_t)(unsigned)p6 * N_HID + h];
            float g7 = X[(size_t)(unsigned)p7 * N_HID + h];
            acc += __uint_as_float((unsigned)(p0 >> 32)) * g0;
            acc += (rem > 1) ? __uint_as_float((unsigned)(p1 >> 32)) * g1 : 0.f;
            acc += (rem > 2) ? __uint_as_float((unsigned)(p2 >> 32)) * g2 : 0.f;
            acc += (rem > 3) ? __uint_as_float((unsigned)(p3 >> 32)) * g3 : 0.f;
            acc += (rem > 4) ? __uint_as_float((unsigned)(p4 >> 32)) * g4 : 0.f;
            acc += (rem > 5) ? __uint_as_float((unsigned)(p5 >> 32)) * g5 : 0.f;
            acc += (rem > 6) ? __uint_as_float((unsigned)(p6 >> 32)) * g6 : 0.f;
            acc += (rem > 7) ? __uint_as_float((unsigned)(p7 >> 32)) * g7 : 0.f;
        }
        float lv = (acc >= 0.f) ? acc : 0.5f * acc;
        float ss = lv * lv;
#pragma unroll
        for (int off = 32; off > 0; off >>= 1) ss += __shfl_xor(ss, off, 64);
        size_t idx = (size_t)row * N_HID + h;
        out[idx] += lv / fmaxf(sqrtf(ss), 1e-12f);
        if (FUSE) {
            sm[wave][h] = lv;
            asm volatile("s_waitcnt lgkmcnt(0)" ::: "memory");
            float bacc = 0.f;
#pragma unroll
            for (int k = 0; k < N_HID; k += 4) {
                float4 x4 = *(const float4*)&sm[wave][k];
                bacc += x4.x * w[k] + x4.y * w[k+1] + x4.z * w[k+2] + x4.w * w[k+3];
            }
            Bout[idx] = bacc;
        }
        s = e;
    }
}

// ===========================================================================
// Fallback (R0 atomic path) — only if ws_size too small
// ===========================================================================
__global__ __launch_bounds__(256) void init_concat(const float* __restrict__ u,
                                                   const float* __restrict__ it,
                                                   float* __restrict__ A,
                                                   float* __restrict__ out) {
    int i = blockIdx.x * 256 + threadIdx.x;
    const int nu4 = N_USER * N_HID / 4;
    const int nt4 = N_NODES * N_HID / 4;
    if (i >= nt4) return;
    float4 v = (i < nu4) ? ((const float4*)u)[i] : ((const float4*)it)[i - nu4];
    ((float4*)A)[i]   = v;
    ((float4*)out)[i] = v;
}

__global__ __launch_bounds__(256) void copy2(const float* __restrict__ src,
                                             float* __restrict__ d0,
                                             float* __restrict__ d1, int n4) {
    int i = blockIdx.x * 256 + threadIdx.x;
    if (i >= n4) return;
    float4 v = ((const float4*)src)[i];
    ((float4*)d0)[i] = v;
    ((float4*)d1)[i] = v;
}

__global__ __launch_bounds__(256) void gemm64(const float* __restrict__ X,
                                              const float* __restrict__ W,
                                              float* __restrict__ Y, int nrows) {
    __shared__ float Ws[N_HID * N_HID];
    int tid = threadIdx.x;
#pragma unroll
    for (int c = 0; c < 16; ++c) Ws[c * 256 + tid] = W[c * 256 + tid];
    __syncthreads();
    int row = blockIdx.x * 256 + tid;
    if (row >= nrows) return;
    float x[N_HID];
    const float4* xr = (const float4*)(X + (size_t)row * N_HID);
#pragma unroll
    for (int c = 0; c < 16; ++c) {
        float4 v = xr[c];
        x[4*c+0] = v.x; x[4*c+1] = v.y; x[4*c+2] = v.z; x[4*c+3] = v.w;
    }
    float4* y4 = (float4*)(Y + (size_t)row * N_HID);
    for (int jc = 0; jc < 16; ++jc) {
        float4 a = make_float4(0.f,0.f,0.f,0.f);
#pragma unroll
        for (int k = 0; k < N_HID; ++k) {
            float4 wv = *((const float4*)&Ws[k * N_HID + jc * 4]);
            a.x += x[k]*wv.x; a.y += x[k]*wv.y; a.z += x[k]*wv.z; a.w += x[k]*wv.w;
        }
        y4[jc] = a;
    }
}

__global__ __launch_bounds__(256) void spmm_scatter(const int* __restrict__ rows,
                                                    const int* __restrict__ cols,
                                                    const float* __restrict__ vals,
                                                    const float* __restrict__ X,
                                                    float* __restrict__ Y, int nedges) {
    long long t = (long long)blockIdx.x * 256 + threadIdx.x;
    int e = (int)(t >> 6);
    int h = (int)(t & 63);
    if (e >= nedges) return;
    atomicAdd(&Y[rows[e] * N_HID + h], vals[e] * X[cols[e] * N_HID + h]);
}

__global__ __launch_bounds__(256) void leaky_norm_acc(float* __restrict__ Y,
                                                      float* __restrict__ out, int nrows) {
    int row = blockIdx.x * 4 + (threadIdx.x >> 6);
    int h   = threadIdx.x & 63;
    if (row >= nrows) return;
    int idx = row * N_HID + h;
    float v = Y[idx];
    v = (v >= 0.f) ? v : 0.5f * v;
    Y[idx] = v;
    float s = v * v;
#pragma unroll
    for (int off = 32; off > 0; off >>= 1) s += __shfl_xor(s, off, 64);
    out[idx] += v / fmaxf(sqrtf(s), 1e-12f);
}

// ===========================================================================
extern "C" void kernel_launch(void* const* d_in, const int* in_sizes, int n_in,
                              void* d_out, int out_size, void* d_ws, size_t ws_size,
                              hipStream_t stream) {
    const float* user_emb = (const float*)d_in[0];
    const float* item_emb = (const float*)d_in[1];
    const float* ui_w     = (const float*)d_in[2];
    const float* s_w      = (const float*)d_in[3];
    const int*   ui_rows  = (const int*)d_in[4];
    const int*   ui_cols  = (const int*)d_in[5];
    const float* ui_vals  = (const float*)d_in[6];
    const int*   s_rows   = (const int*)d_in[7];
    const int*   s_cols   = (const int*)d_in[8];
    const float* s_vals   = (const float*)d_in[9];

    float* out_ui = (float*)d_out;
    float* out_s  = (float*)d_out + (size_t)N_NODES * N_HID;

    const size_t bufBytes = (size_t)N_NODES * N_HID * sizeof(float);   // 64 MB
    float* B1 = (float*)d_ws;
    float* B2 = (float*)((char*)d_ws + bufBytes);

    const size_t pairsOff    = 2 * bufBytes;                    // 128,000,000
    const size_t rowStartOff = pairsOff + (size_t)E_TOT * 8;    // +16,000,000
    const size_t rowCurOff   = rowStartOff + 1400832;           // (N_TOT+1)*4 padded
    const size_t sumsOff     = rowCurOff + 1400832;
    const size_t needBytes   = sumsOff + 8192;                  // ≈146.8 MB

    if (ws_size >= needBytes) {
        ull* pairs     = (ull*)((char*)d_ws + pairsOff);
        int* rowStart  = (int*)((char*)d_ws + rowStartOff);     // N_TOT + 1
        int* rowCur    = (int*)((char*)d_ws + rowCurOff);
        int* blockSums = (int*)((char*)d_ws + sumsOff);

        const int nbScan = (N_TOT + 511) / 512;                 // 684 ≤ 1024
        const int nbE    = (E_TOT + 255) / 256;

        // ---- combined sort (runs once for both graphs) ----
        hipMemsetAsync(rowStart, 0, (size_t)N_TOT * 4, stream);
        edge_hist2<<<nbE, 256, 0, stream>>>(ui_rows, s_rows, rowStart);
        scan_block512<<<nbScan, 256, 0, stream>>>(rowStart, blockSums, N_TOT);
        scan_sums<<<1, 1024, 0, stream>>>(blockSums, nbScan);
        scan_add512<<<nbScan, 256, 0, stream>>>(rowStart, rowCur, blockSums, N_TOT, E_TOT);
        edge_scatter2<<<nbE, 256, 0, stream>>>(ui_rows, ui_cols, ui_vals,
                                               s_rows, s_cols, s_vals, rowCur, pairs);

        // ---- UI branch: 3 kernels ----
        {
            const int RPW_G = 16, RPW_F = 16, RPW_L = 4;
            gemm_init<<<(N_NODES + 4*RPW_G - 1) / (4*RPW_G), 256, 0, stream>>>(
                user_emb, item_emb, N_USER, ui_w, B1, out_ui, N_NODES, RPW_G);
            spmm_fused2<true><<<(N_NODES + 4*RPW_F - 1) / (4*RPW_F), 256, 0, stream>>>(
                pairs, rowStart, B1, ui_w + N_HID * N_HID, B2, out_ui, N_NODES, RPW_F);
            spmm_fused2<false><<<(N_NODES + 4*RPW_L - 1) / (4*RPW_L), 256, 0, stream>>>(
                pairs, rowStart, B2, nullptr, nullptr, out_ui, N_NODES, RPW_L);
        }
        // ---- social branch: 3 kernels ----
        {
            const int RPW_G = 16, RPW_F = 16, RPW_L = 4;
            gemm_init<<<(N_USER + 4*RPW_G - 1) / (4*RPW_G), 256, 0, stream>>>(
                user_emb, user_emb, N_USER, s_w, B1, out_s, N_USER, RPW_G);
            spmm_fused2<true><<<(N_USER + 4*RPW_F - 1) / (4*RPW_F), 256, 0, stream>>>(
                pairs, rowStart + N_NODES, B1, s_w + N_HID * N_HID, B2, out_s, N_USER, RPW_F);
            spmm_fused2<false><<<(N_USER + 4*RPW_L - 1) / (4*RPW_L), 256, 0, stream>>>(
                pairs, rowStart + N_NODES, B2, nullptr, nullptr, out_s, N_USER, RPW_L);
        }
        return;
    }

    // ------------------- fallback: R0 atomic path -------------------
    float* A = B1;
    float* B = B2;
    init_concat<<<(N_NODES * N_HID / 4 + 255) / 256, 256, 0, stream>>>(
        user_emb, item_emb, A, out_ui);
    for (int l = 0; l < 2; ++l) {
        gemm64<<<(N_NODES + 255) / 256, 256, 0, stream>>>(
            A, ui_w + l * N_HID * N_HID, B, N_NODES);
        hipMemsetAsync(A, 0, bufBytes, stream);
        spmm_scatter<<<(int)(((long long)E_UI * 64) / 256), 256, 0, stream>>>(
            ui_rows, ui_cols, ui_vals, B, A, E_UI);
        leaky_norm_acc<<<(N_NODES + 3) / 4, 256, 0, stream>>>(A, out_ui, N_NODES);
    }
    copy2<<<(N_USER * N_HID / 4 + 255) / 256, 256, 0, stream>>>(
        user_emb, A, out_s, N_USER * N_HID / 4);
    const size_t sBytes = (size_t)N_USER * N_HID * sizeof(float);
    for (int l = 0; l < 2; ++l) {
        gemm64<<<(N_USER + 255) / 256, 256, 0, stream>>>(
            A, s_w + l * N_HID * N_HID, B, N_USER);
        hipMemsetAsync(A, 0, sBytes, stream);
        spmm_scatter<<<(int)(((long long)E_S * 64) / 256), 256, 0, stream>>>(
            s_rows, s_cols, s_vals, B, A, E_S);
        leaky_norm_acc<<<(N_USER + 3) / 4, 256, 0, stream>>>(A, out_s, N_USER);
    }
}

// Round 4
// 514.959 us; speedup vs baseline: 2.4073x; 1.3404x over previous
//
#include <hip/hip_runtime.h>

#define N_USER   100000
#define N_ITEM   150000
#define N_NODES  250000
#define N_HID    64
#define E_UI     1000000
#define E_S      1000000
#define N_TOT    (N_NODES + N_USER)      // 350000
#define E_TOT    (E_UI + E_S)            // 2000000

#define BR    64                          // rows per block (spmm/gemm)
#define SMSTR 68                          // padded x-stage row stride (floats)

typedef unsigned long long ull;

// ===========================================================================
// Combined counting sort; social rows AND cols baked with +N_NODES
// ===========================================================================
__global__ __launch_bounds__(256) void edge_hist2(const int* __restrict__ ui_rows,
                                                  const int* __restrict__ s_rows,
                                                  int* __restrict__ counts) {
    int i = blockIdx.x * 256 + threadIdx.x;
    if (i < E_UI)            atomicAdd(&counts[ui_rows[i]], 1);
    else if (i < E_TOT)      atomicAdd(&counts[N_NODES + s_rows[i - E_UI]], 1);
}

__global__ __launch_bounds__(256) void scan_block512(int* __restrict__ data,
                                                     int* __restrict__ blockSums, int n) {
    __shared__ int sm[512];
    int t = threadIdx.x;
    int base = blockIdx.x * 512;
    int i0 = base + t, i1 = base + t + 256;
    int v0 = (i0 < n) ? data[i0] : 0;
    int v1 = (i1 < n) ? data[i1] : 0;
    sm[t] = v0; sm[t + 256] = v1;
    __syncthreads();
    for (int off = 1; off < 512; off <<= 1) {
        int a = (t >= off) ? sm[t - off] : 0;
        int b = (t + 256 >= off) ? sm[t + 256 - off] : 0;
        __syncthreads();
        sm[t] += a; sm[t + 256] += b;
        __syncthreads();
    }
    if (i0 < n) data[i0] = sm[t] - v0;
    if (i1 < n) data[i1] = sm[t + 256] - v1;
    if (t == 255) blockSums[blockIdx.x] = sm[511];
}

__global__ __launch_bounds__(1024) void scan_sums(int* __restrict__ blockSums, int nb) {
    __shared__ int sm[1024];
    int v = (threadIdx.x < nb) ? blockSums[threadIdx.x] : 0;
    sm[threadIdx.x] = v;
    __syncthreads();
    for (int off = 1; off < 1024; off <<= 1) {
        int t = (threadIdx.x >= off) ? sm[threadIdx.x - off] : 0;
        __syncthreads();
        sm[threadIdx.x] += t;
        __syncthreads();
    }
    if (threadIdx.x < nb) blockSums[threadIdx.x] = sm[threadIdx.x] - v;
}

__global__ __launch_bounds__(256) void scan_add512(int* __restrict__ data,
                                                   int* __restrict__ rowCur,
                                                   const int* __restrict__ blockSums,
                                                   int n, int total) {
    int base = blockIdx.x * 512;
    int s = blockSums[blockIdx.x];
#pragma unroll
    for (int k = 0; k < 2; ++k) {
        int i = base + threadIdx.x + k * 256;
        if (i < n) { int v = data[i] + s; data[i] = v; rowCur[i] = v; }
    }
    if (blockIdx.x == 0 && threadIdx.x == 0) data[n] = total;
}

__global__ __launch_bounds__(256) void edge_scatter2(const int* __restrict__ ui_rows,
                                                     const int* __restrict__ ui_cols,
                                                     const float* __restrict__ ui_vals,
                                                     const int* __restrict__ s_rows,
                                                     const int* __restrict__ s_cols,
                                                     const float* __restrict__ s_vals,
                                                     int* __restrict__ rowCur,
                                                     ull* __restrict__ pairs) {
    int i = blockIdx.x * 256 + threadIdx.x;
    int r, c; float v;
    if (i < E_UI)       { r = ui_rows[i];          c = ui_cols[i];            v = ui_vals[i]; }
    else if (i < E_TOT) { int k = i - E_UI;
                          r = N_NODES + s_rows[k]; c = N_NODES + s_cols[k];   v = s_vals[k]; }
    else return;
    int pos = atomicAdd(&rowCur[r], 1);
    pairs[pos] = (ull)(unsigned)c | ((ull)__float_as_uint(v) << 32);
}

// ===========================================================================
// gemm_init: region-split; wave per 16 rows, lane = h. out=x ; B = x @ W
// ===========================================================================
__global__ __launch_bounds__(256) void gemm_init_m(const float* __restrict__ u,
                                                   const float* __restrict__ it,
                                                   const float* __restrict__ Wui,
                                                   const float* __restrict__ Wsoc,
                                                   float* __restrict__ B,
                                                   float* __restrict__ out_ui,
                                                   float* __restrict__ out_s,
                                                   int uiRows, int uiBlocks, int sRows) {
    __shared__ float sm[4][N_HID];
    const bool isUI = (int)blockIdx.x < uiBlocks;
    const int bl    = isUI ? blockIdx.x : blockIdx.x - uiBlocks;
    const int rbeg  = isUI ? bl * BR : N_NODES + bl * BR;
    const int rlim  = isUI ? min(BR, uiRows - bl * BR) : min(BR, sRows - bl * BR);
    const int w = threadIdx.x >> 6;
    const int h = threadIdx.x & 63;
    const float* W = isUI ? Wui : Wsoc;
    float wreg[N_HID];
#pragma unroll
    for (int k = 0; k < N_HID; ++k) wreg[k] = W[k * N_HID + h];

    int r0 = rbeg + w * 16;
    int r1 = min(r0 + 16, rbeg + rlim);
    for (int row = r0; row < r1; ++row) {
        const float* src;
        float* op; size_t orow;
        if (isUI) {
            src = (row < N_USER) ? u + (size_t)row * N_HID
                                 : it + (size_t)(row - N_USER) * N_HID;
            op = out_ui; orow = row;
        } else {
            src = u + (size_t)(row - N_NODES) * N_HID;
            op = out_s; orow = row - N_NODES;
        }
        float x = src[h];
        op[orow * N_HID + h] = x;
        sm[w][h] = x;
        asm volatile("s_waitcnt lgkmcnt(0)" ::: "memory");
        float bacc = 0.f;
#pragma unroll
        for (int k = 0; k < N_HID; k += 4) {
            float4 x4 = *(const float4*)&sm[w][k];
            bacc = fmaf(x4.x, wreg[k],   bacc);
            bacc = fmaf(x4.y, wreg[k+1], bacc);
            bacc = fmaf(x4.z, wreg[k+2], bacc);
            bacc = fmaf(x4.w, wreg[k+3], bacc);
        }
        B[(size_t)row * N_HID + h] = bacc;
    }
}

// ===========================================================================
// spmm_q: quarter-wave (16 lanes, float4/lane) per destination row.
//   acc = sum_e val*X[col] ; lv = leaky(acc) ; out += lv/||lv|| ;
//   FUSE: Bout[row] = lv @ W2  (W2 staged in LDS per block)
// ===========================================================================
template <bool FUSE>
__global__ __launch_bounds__(256) void spmm_q(const ull* __restrict__ pairs,
                                              const int* __restrict__ rowStart,
                                              const float* __restrict__ X,
                                              const float* __restrict__ Wui,
                                              const float* __restrict__ Wsoc,
                                              float* __restrict__ Bout,
                                              float* __restrict__ out_ui,
                                              float* __restrict__ out_s,
                                              int uiRows, int uiBlocks, int sRows) {
    __shared__ float Wsm[FUSE ? (N_HID * N_HID) : 4];
    __shared__ float smX[4][4 * SMSTR];
    const int tid = threadIdx.x;
    const bool isUI = (int)blockIdx.x < uiBlocks;
    const int bl    = isUI ? blockIdx.x : blockIdx.x - uiBlocks;
    const int rbeg  = isUI ? bl * BR : N_NODES + bl * BR;
    const int rlim  = isUI ? min(BR, uiRows - bl * BR) : min(BR, sRows - bl * BR);

    if (FUSE) {
        const float* W2 = isUI ? Wui : Wsoc;
#pragma unroll
        for (int c = 0; c < 4; ++c)
            *(float4*)&Wsm[c * 1024 + tid * 4] = *(const float4*)&W2[c * 1024 + tid * 4];
        __syncthreads();
    }

    const int w  = tid >> 6;
    const int q  = (tid >> 4) & 3;
    const int l4 = (tid & 15) * 4;
    float* smx = &smX[w][q * SMSTR];

    // interleaved rows: iteration i, quarter q -> row rbeg + w*16 + i*4 + q
    for (int i = 0; i < 4; ++i) {
        int row = rbeg + w * 16 + i * 4 + q;
        if (row >= rbeg + rlim) break;
        int s = rowStart[row];
        int e = rowStart[row + 1];
        float4 acc = make_float4(0.f, 0.f, 0.f, 0.f);
        for (int j = s; j < e; j += 4) {
            int last = e - 1;
            ull p0 = pairs[j];
            ull p1 = pairs[min(j + 1, last)];
            ull p2 = pairs[min(j + 2, last)];
            ull p3 = pairs[min(j + 3, last)];
            float v0 = __uint_as_float((unsigned)(p0 >> 32));
            float v1 = (j + 1 < e) ? __uint_as_float((unsigned)(p1 >> 32)) : 0.f;
            float v2 = (j + 2 < e) ? __uint_as_float((unsigned)(p2 >> 32)) : 0.f;
            float v3 = (j + 3 < e) ? __uint_as_float((unsigned)(p3 >> 32)) : 0.f;
            const float4 g0 = *(const float4*)(X + ((unsigned)p0 * (unsigned)N_HID + l4));
            const float4 g1 = *(const float4*)(X + ((unsigned)p1 * (unsigned)N_HID + l4));
            const float4 g2 = *(const float4*)(X + ((unsigned)p2 * (unsigned)N_HID + l4));
            const float4 g3 = *(const float4*)(X + ((unsigned)p3 * (unsigned)N_HID + l4));
            acc.x = fmaf(v0, g0.x, acc.x); acc.y = fmaf(v0, g0.y, acc.y);
            acc.z = fmaf(v0, g0.z, acc.z); acc.w = fmaf(v0, g0.w, acc.w);
            acc.x = fmaf(v1, g1.x, acc.x); acc.y = fmaf(v1, g1.y, acc.y);
            acc.z = fmaf(v1, g1.z, acc.z); acc.w = fmaf(v1, g1.w, acc.w);
            acc.x = fmaf(v2, g2.x, acc.x); acc.y = fmaf(v2, g2.y, acc.y);
            acc.z = fmaf(v2, g2.z, acc.z); acc.w = fmaf(v2, g2.w, acc.w);
            acc.x = fmaf(v3, g3.x, acc.x); acc.y = fmaf(v3, g3.y, acc.y);
            acc.z = fmaf(v3, g3.z, acc.z); acc.w = fmaf(v3, g3.w, acc.w);
        }
        float4 lv;
        lv.x = (acc.x >= 0.f) ? acc.x : 0.5f * acc.x;
        lv.y = (acc.y >= 0.f) ? acc.y : 0.5f * acc.y;
        lv.z = (acc.z >= 0.f) ? acc.z : 0.5f * acc.z;
        lv.w = (acc.w >= 0.f) ? acc.w : 0.5f * acc.w;
        float ss = lv.x * lv.x + lv.y * lv.y + lv.z * lv.z + lv.w * lv.w;
        ss += __shfl_xor(ss, 1, 64);
        ss += __shfl_xor(ss, 2, 64);
        ss += __shfl_xor(ss, 4, 64);
        ss += __shfl_xor(ss, 8, 64);
        float inv = 1.f / fmaxf(sqrtf(ss), 1e-12f);

        float* op = isUI ? out_ui + (size_t)row * N_HID
                         : out_s  + (size_t)(row - N_NODES) * N_HID;
        float4 o = *(float4*)&op[l4];
        o.x = fmaf(lv.x, inv, o.x); o.y = fmaf(lv.y, inv, o.y);
        o.z = fmaf(lv.z, inv, o.z); o.w = fmaf(lv.w, inv, o.w);
        *(float4*)&op[l4] = o;

        if (FUSE) {
            *(float4*)&smx[l4] = lv;
            asm volatile("s_waitcnt lgkmcnt(0)" ::: "memory");
            float4 b = make_float4(0.f, 0.f, 0.f, 0.f);
#pragma unroll
            for (int k4 = 0; k4 < 16; ++k4) {
                float4 x4 = *(const float4*)&smx[k4 * 4];
                const float* wr = &Wsm[(k4 * 4) * N_HID + l4];
                float4 w0 = *(const float4*)(wr);
                float4 w1 = *(const float4*)(wr + N_HID);
                float4 w2 = *(const float4*)(wr + 2 * N_HID);
                float4 w3 = *(const float4*)(wr + 3 * N_HID);
                b.x = fmaf(x4.x, w0.x, b.x); b.x = fmaf(x4.y, w1.x, b.x);
                b.x = fmaf(x4.z, w2.x, b.x); b.x = fmaf(x4.w, w3.x, b.x);
                b.y = fmaf(x4.x, w0.y, b.y); b.y = fmaf(x4.y, w1.y, b.y);
                b.y = fmaf(x4.z, w2.y, b.y); b.y = fmaf(x4.w, w3.y, b.y);
                b.z = fmaf(x4.x, w0.z, b.z); b.z = fmaf(x4.y, w1.z, b.z);
                b.z = fmaf(x4.z, w2.z, b.z); b.z = fmaf(x4.w, w3.z, b.z);
                b.w = fmaf(x4.x, w0.w, b.w); b.w = fmaf(x4.y, w1.w, b.w);
                b.w = fmaf(x4.z, w2.w, b.w); b.w = fmaf(x4.w, w3.w, b.w);
            }
            *(float4*)&Bout[(size_t)row * N_HID + l4] = b;
        }
    }
}

// ===========================================================================
// Atomic fallback (only if ws too small for the sorted path)
// ===========================================================================
__global__ __launch_bounds__(256) void init_concat(const float* __restrict__ u,
                                                   const float* __restrict__ it,
                                                   float* __restrict__ A,
                                                   float* __restrict__ out) {
    int i = blockIdx.x * 256 + threadIdx.x;
    const int nu4 = N_USER * N_HID / 4;
    const int nt4 = N_NODES * N_HID / 4;
    if (i >= nt4) return;
    float4 v = (i < nu4) ? ((const float4*)u)[i] : ((const float4*)it)[i - nu4];
    ((float4*)A)[i]   = v;
    ((float4*)out)[i] = v;
}

__global__ __launch_bounds__(256) void copy2(const float* __restrict__ src,
                                             float* __restrict__ d0,
                                             float* __restrict__ d1, int n4) {
    int i = blockIdx.x * 256 + threadIdx.x;
    if (i >= n4) return;
    float4 v = ((const float4*)src)[i];
    ((float4*)d0)[i] = v;
    ((float4*)d1)[i] = v;
}

__global__ __launch_bounds__(256) void gemm64(const float* __restrict__ X,
                                              const float* __restrict__ W,
                                              float* __restrict__ Y, int nrows) {
    __shared__ float Ws[N_HID * N_HID];
    int tid = threadIdx.x;
#pragma unroll
    for (int c = 0; c < 16; ++c) Ws[c * 256 + tid] = W[c * 256 + tid];
    __syncthreads();
    int row = blockIdx.x * 256 + tid;
    if (row >= nrows) return;
    float x[N_HID];
    const float4* xr = (const float4*)(X + (size_t)row * N_HID);
#pragma unroll
    for (int c = 0; c < 16; ++c) {
        float4 v = xr[c];
        x[4*c+0] = v.x; x[4*c+1] = v.y; x[4*c+2] = v.z; x[4*c+3] = v.w;
    }
    float4* y4 = (float4*)(Y + (size_t)row * N_HID);
    for (int jc = 0; jc < 16; ++jc) {
        float4 a = make_float4(0.f,0.f,0.f,0.f);
#pragma unroll
        for (int k = 0; k < N_HID; ++k) {
            float4 wv = *((const float4*)&Ws[k * N_HID + jc * 4]);
            a.x += x[k]*wv.x; a.y += x[k]*wv.y; a.z += x[k]*wv.z; a.w += x[k]*wv.w;
        }
        y4[jc] = a;
    }
}

__global__ __launch_bounds__(256) void spmm_scatter(const int* __restrict__ rows,
                                                    const int* __restrict__ cols,
                                                    const float* __restrict__ vals,
                                                    const float* __restrict__ X,
                                                    float* __restrict__ Y, int nedges) {
    long long t = (long long)blockIdx.x * 256 + threadIdx.x;
    int e = (int)(t >> 6);
    int h = (int)(t & 63);
    if (e >= nedges) return;
    atomicAdd(&Y[rows[e] * N_HID + h], vals[e] * X[cols[e] * N_HID + h]);
}

__global__ __launch_bounds__(256) void leaky_norm_acc(float* __restrict__ Y,
                                                      float* __restrict__ out, int nrows) {
    int row = blockIdx.x * 4 + (threadIdx.x >> 6);
    int h   = threadIdx.x & 63;
    if (row >= nrows) return;
    int idx = row * N_HID + h;
    float v = Y[idx];
    v = (v >= 0.f) ? v : 0.5f * v;
    Y[idx] = v;
    float s = v * v;
#pragma unroll
    for (int off = 32; off > 0; off >>= 1) s += __shfl_xor(s, off, 64);
    out[idx] += v / fmaxf(sqrtf(s), 1e-12f);
}

// ===========================================================================
extern "C" void kernel_launch(void* const* d_in, const int* in_sizes, int n_in,
                              void* d_out, int out_size, void* d_ws, size_t ws_size,
                              hipStream_t stream) {
    const float* user_emb = (const float*)d_in[0];
    const float* item_emb = (const float*)d_in[1];
    const float* ui_w     = (const float*)d_in[2];
    const float* s_w      = (const float*)d_in[3];
    const int*   ui_rows  = (const int*)d_in[4];
    const int*   ui_cols  = (const int*)d_in[5];
    const float* ui_vals  = (const float*)d_in[6];
    const int*   s_rows   = (const int*)d_in[7];
    const int*   s_cols   = (const int*)d_in[8];
    const float* s_vals   = (const float*)d_in[9];

    float* out_ui = (float*)d_out;
    float* out_s  = (float*)d_out + (size_t)N_NODES * N_HID;

    const size_t szUI  = (size_t)N_NODES * N_HID * sizeof(float);   // 64.0 MB
    const size_t szTOT = (size_t)N_TOT   * N_HID * sizeof(float);   // 89.6 MB
    const size_t rsPad = 1400832;                                   // (N_TOT+1)*4 padded

    const int uiBlocks = (N_NODES + BR - 1) / BR;    // 3907
    const int sBlocks  = (N_USER  + BR - 1) / BR;    // 1563
    const int nbScan   = (N_TOT + 511) / 512;
    const int nbE      = (E_TOT + 255) / 256;

    // decide schedule by workspace size
    const size_t mergedNeed = 2 * szTOT + (size_t)E_TOT * 8 + 2 * rsPad + 8192; // ~198.0 MB
    const size_t branchNeed = 2 * szUI  + (size_t)E_TOT * 8 + 2 * rsPad + 8192; // ~146.8 MB

    if (ws_size >= branchNeed) {
        const bool merged = (ws_size >= mergedNeed);
        const size_t bsz  = merged ? szTOT : szUI;
        float* B1 = (float*)d_ws;
        float* B2 = (float*)((char*)d_ws + bsz);
        char*  p  = (char*)d_ws + 2 * bsz;
        ull* pairs     = (ull*)p;            p += (size_t)E_TOT * 8;
        int* rowStart  = (int*)p;            p += rsPad;
        int* rowCur    = (int*)p;            p += rsPad;
        int* blockSums = (int*)p;

        // ---- combined sort (social ids baked +N_NODES) ----
        hipMemsetAsync(rowStart, 0, (size_t)N_TOT * 4, stream);
        edge_hist2<<<nbE, 256, 0, stream>>>(ui_rows, s_rows, rowStart);
        scan_block512<<<nbScan, 256, 0, stream>>>(rowStart, blockSums, N_TOT);
        scan_sums<<<1, 1024, 0, stream>>>(blockSums, nbScan);
        scan_add512<<<nbScan, 256, 0, stream>>>(rowStart, rowCur, blockSums, N_TOT, E_TOT);
        edge_scatter2<<<nbE, 256, 0, stream>>>(ui_rows, ui_cols, ui_vals,
                                               s_rows, s_cols, s_vals, rowCur, pairs);

        const float* Wui2 = ui_w + N_HID * N_HID;
        const float* Ws2  = s_w  + N_HID * N_HID;
        const size_t socOff = (size_t)N_NODES * N_HID;   // float offset of social region

        if (merged) {
            const int grid = uiBlocks + sBlocks;         // 5470
            gemm_init_m<<<grid, 256, 0, stream>>>(user_emb, item_emb, ui_w, s_w,
                                                  B1, out_ui, out_s,
                                                  N_NODES, uiBlocks, N_USER);
            spmm_q<true><<<grid, 256, 0, stream>>>(pairs, rowStart, B1, Wui2, Ws2,
                                                   B2, out_ui, out_s,
                                                   N_NODES, uiBlocks, N_USER);
            spmm_q<false><<<grid, 256, 0, stream>>>(pairs, rowStart, B2, nullptr, nullptr,
                                                    B1, out_ui, out_s,
                                                    N_NODES, uiBlocks, N_USER);
        } else {
            // per-branch; social region accessed through -N_NODES-row shifted bases
            float* B1s = (float*)((char*)B1 - socOff * sizeof(float));
            float* B2s = (float*)((char*)B2 - socOff * sizeof(float));
            // UI branch
            gemm_init_m<<<uiBlocks, 256, 0, stream>>>(user_emb, item_emb, ui_w, s_w,
                                                      B1, out_ui, out_s,
                                                      N_NODES, uiBlocks, 0);
            spmm_q<true><<<uiBlocks, 256, 0, stream>>>(pairs, rowStart, B1, Wui2, Ws2,
                                                       B2, out_ui, out_s,
                                                       N_NODES, uiBlocks, 0);
            spmm_q<false><<<uiBlocks, 256, 0, stream>>>(pairs, rowStart, B2, nullptr, nullptr,
                                                        B1, out_ui, out_s,
                                                        N_NODES, uiBlocks, 0);
            // social branch
            gemm_init_m<<<sBlocks, 256, 0, stream>>>(user_emb, item_emb, ui_w, s_w,
                                                     B1s, out_ui, out_s,
                                                     0, 0, N_USER);
            spmm_q<true><<<sBlocks, 256, 0, stream>>>(pairs, rowStart, B1s, Wui2, Ws2,
                                                      B2s, out_ui, out_s,
                                                      0, 0, N_USER);
            spmm_q<false><<<sBlocks, 256, 0, stream>>>(pairs, rowStart, B2s, nullptr, nullptr,
                                                       B1s, out_ui, out_s,
                                                       0, 0, N_USER);
        }
        return;
    }

    // ------------------- fallback: atomic path -------------------
    float* A = (float*)d_ws;
    float* B = (float*)((char*)d_ws + szUI);
    init_concat<<<(N_NODES * N_HID / 4 + 255) / 256, 256, 0, stream>>>(
        user_emb, item_emb, A, out_ui);
    for (int l = 0; l < 2; ++l) {
        gemm64<<<(N_NODES + 255) / 256, 256, 0, stream>>>(
            A, ui_w + l * N_HID * N_HID, B, N_NODES);
        hipMemsetAsync(A, 0, szUI, stream);
        spmm_scatter<<<(int)(((long long)E_UI * 64) / 256), 256, 0, stream>>>(
            ui_rows, ui_cols, ui_vals, B, A, E_UI);
        leaky_norm_acc<<<(N_NODES + 3) / 4, 256, 0, stream>>>(A, out_ui, N_NODES);
    }
    copy2<<<(N_USER * N_HID / 4 + 255) / 256, 256, 0, stream>>>(
        user_emb, A, out_s, N_USER * N_HID / 4);
    const size_t sBytes = (size_t)N_USER * N_HID * sizeof(float);
    for (int l = 0; l < 2; ++l) {
        gemm64<<<(N_USER + 255) / 256, 256, 0, stream>>>(
            A, s_w + l * N_HID * N_HID, B, N_USER);
        hipMemsetAsync(A, 0, sBytes, stream);
        spmm_scatter<<<(int)(((long long)E_S * 64) / 256), 256, 0, stream>>>(
            s_rows, s_cols, s_vals, B, A, E_S);
        leaky_norm_acc<<<(N_USER + 3) / 4, 256, 0, stream>>>(A, out_s, N_USER);
    }
}

// Round 5
// 472.874 us; speedup vs baseline: 2.6215x; 1.0890x over previous
//
#include <hip/hip_runtime.h>

#define N_USER   100000
#define N_ITEM   150000
#define N_NODES  250000
#define N_HID    64
#define E_UI     1000000
#define E_S      1000000
#define N_TOT    (N_NODES + N_USER)      // 350000
#define E_TOT    (E_UI + E_S)            // 2000000

#define BR     64                         // rows per block (spmm/gemm)
#define SMSTR  68                         // padded x-stage row stride (floats)
#define CH     4096                       // edges per bin_pass1 chunk
#define RPB    2048                       // rows per coarse bucket
#define RPB_SH 11
#define NBKT   ((N_TOT + RPB - 1) / RPB)  // 171

typedef unsigned long long ull;

// ===========================================================================
// histogram + scan (CSR rowStart over combined 350K rows)
// ===========================================================================
__global__ __launch_bounds__(256) void edge_hist2(const int* __restrict__ ui_rows,
                                                  const int* __restrict__ s_rows,
                                                  int* __restrict__ counts) {
    int i = blockIdx.x * 256 + threadIdx.x;
    if (i < E_UI)            atomicAdd(&counts[ui_rows[i]], 1);
    else if (i < E_TOT)      atomicAdd(&counts[N_NODES + s_rows[i - E_UI]], 1);
}

__global__ __launch_bounds__(256) void scan_block512(int* __restrict__ data,
                                                     int* __restrict__ blockSums, int n) {
    __shared__ int sm[512];
    int t = threadIdx.x;
    int base = blockIdx.x * 512;
    int i0 = base + t, i1 = base + t + 256;
    int v0 = (i0 < n) ? data[i0] : 0;
    int v1 = (i1 < n) ? data[i1] : 0;
    sm[t] = v0; sm[t + 256] = v1;
    __syncthreads();
    for (int off = 1; off < 512; off <<= 1) {
        int a = (t >= off) ? sm[t - off] : 0;
        int b = (t + 256 >= off) ? sm[t + 256 - off] : 0;
        __syncthreads();
        sm[t] += a; sm[t + 256] += b;
        __syncthreads();
    }
    if (i0 < n) data[i0] = sm[t] - v0;
    if (i1 < n) data[i1] = sm[t + 256] - v1;
    if (t == 255) blockSums[blockIdx.x] = sm[511];
}

__global__ __launch_bounds__(1024) void scan_sums(int* __restrict__ blockSums, int nb) {
    __shared__ int sm[1024];
    int v = (threadIdx.x < nb) ? blockSums[threadIdx.x] : 0;
    sm[threadIdx.x] = v;
    __syncthreads();
    for (int off = 1; off < 1024; off <<= 1) {
        int t = (threadIdx.x >= off) ? sm[threadIdx.x - off] : 0;
        __syncthreads();
        sm[threadIdx.x] += t;
        __syncthreads();
    }
    if (threadIdx.x < nb) blockSums[threadIdx.x] = sm[threadIdx.x] - v;
}

// finalize rowStart, and seed per-bucket write cursors at bucket starts
__global__ __launch_bounds__(256) void scan_add512(int* __restrict__ data,
                                                   const int* __restrict__ blockSums,
                                                   int* __restrict__ bucketCur,
                                                   int n, int total) {
    int base = blockIdx.x * 512;
    int s = blockSums[blockIdx.x];
#pragma unroll
    for (int k = 0; k < 2; ++k) {
        int i = base + threadIdx.x + k * 256;
        if (i < n) {
            int v = data[i] + s;
            data[i] = v;
            if ((i & (RPB - 1)) == 0) bucketCur[i >> RPB_SH] = v;
        }
    }
    if (blockIdx.x == 0 && threadIdx.x == 0) data[n] = total;
}

// ===========================================================================
// pass 1: LDS binning by coarse bucket; coalesced bucket-run writes to pairsA
//   entry = v<<32 | rLow<<19 | c   (rLow<2048: 11 bits @19..29; c<2^19)
// ===========================================================================
__global__ __launch_bounds__(256) void bin_pass1(const int* __restrict__ ui_rows,
                                                 const int* __restrict__ ui_cols,
                                                 const float* __restrict__ ui_vals,
                                                 const int* __restrict__ s_rows,
                                                 const int* __restrict__ s_cols,
                                                 const float* __restrict__ s_vals,
                                                 int* __restrict__ bucketCur,
                                                 ull* __restrict__ pairsA) {
    __shared__ ull            staged[CH];
    __shared__ unsigned short bkt[CH];
    __shared__ unsigned short ord[CH];
    __shared__ int hist[256];
    __shared__ int lstart[256];
    __shared__ int cnt2[256];
    __shared__ int baseg[256];
    const int t = threadIdx.x;
    hist[t] = 0; cnt2[t] = 0;
    __syncthreads();

    const int e0 = blockIdx.x * CH;
    const int n  = min(CH, E_TOT - e0);

    for (int i = t; i < n; i += 256) {
        int g = e0 + i, r, c; float v;
        if (g < E_UI) { r = ui_rows[g];            c = ui_cols[g];            v = ui_vals[g]; }
        else          { int k = g - E_UI;
                        r = N_NODES + s_rows[k];   c = N_NODES + s_cols[k];   v = s_vals[k]; }
        int b = r >> RPB_SH;
        staged[i] = ((ull)__float_as_uint(v) << 32) |
                    ((ull)(unsigned)(r & (RPB - 1)) << 19) | (unsigned)c;
        bkt[i] = (unsigned short)b;
        atomicAdd(&hist[b], 1);
    }
    __syncthreads();

    // exclusive scan of hist into lstart (256 entries, Hillis–Steele)
    int hv = hist[t];
    lstart[t] = hv;
    __syncthreads();
    for (int off = 1; off < 256; off <<= 1) {
        int a = (t >= off) ? lstart[t - off] : 0;
        __syncthreads();
        lstart[t] += a;
        __syncthreads();
    }
    int incl = lstart[t];
    __syncthreads();
    lstart[t] = incl - hv;
    if (t < NBKT && hv > 0) baseg[t] = atomicAdd(&bucketCur[t], hv);
    __syncthreads();

    // group edge indices by bucket
    for (int i = t; i < n; i += 256) {
        int b = bkt[i];
        int l = atomicAdd(&cnt2[b], 1);
        ord[lstart[b] + l] = (unsigned short)i;
    }
    __syncthreads();

    // coalesced run writes
    for (int k = t; k < n; k += 256) {
        int i = ord[k];
        int b = bkt[i];
        pairsA[(size_t)baseg[b] + (k - lstart[b])] = staged[i];
    }
}

// ===========================================================================
// pass 2: per-bucket fine scatter to exact CSR position (LDS cursors,
// writes confined to the bucket's ~94KB window -> L2-local)
// ===========================================================================
__global__ __launch_bounds__(256) void fine_pass2(const ull* __restrict__ pairsA,
                                                  const int* __restrict__ rowStart,
                                                  ull* __restrict__ pairs) {
    __shared__ int cur[RPB + 1];
    const int b = blockIdx.x, t = threadIdx.x;
    const int r0 = b * RPB;
    const int nr = min(RPB, N_TOT - r0);
    for (int i = t; i <= nr; i += 256) cur[i] = rowStart[r0 + i];
    __syncthreads();
    const int s0 = cur[0];
    const int e0 = cur[nr];
    __syncthreads();                       // everyone read s0/e0 before cursors move
    for (int j = s0 + t; j < e0; j += 256) {
        ull e = pairsA[j];
        int rLow = (int)((e >> 19) & (RPB - 1));
        int pos = atomicAdd(&cur[rLow], 1);
        pairs[pos] = (e & 0xFFFFFFFF00000000ull) | (e & 0x7FFFFull);
    }
}

// ===========================================================================
// gemm_init: region-split; wave per 16 rows, lane = h. out=x ; B = x @ W
// ===========================================================================
__global__ __launch_bounds__(256) void gemm_init_m(const float* __restrict__ u,
                                                   const float* __restrict__ it,
                                                   const float* __restrict__ Wui,
                                                   const float* __restrict__ Wsoc,
                                                   float* __restrict__ B,
                                                   float* __restrict__ out_ui,
                                                   float* __restrict__ out_s,
                                                   int uiRows, int uiBlocks, int sRows) {
    __shared__ float sm[4][N_HID];
    const bool isUI = (int)blockIdx.x < uiBlocks;
    const int bl    = isUI ? blockIdx.x : blockIdx.x - uiBlocks;
    const int rbeg  = isUI ? bl * BR : N_NODES + bl * BR;
    const int rlim  = isUI ? min(BR, uiRows - bl * BR) : min(BR, sRows - bl * BR);
    const int w = threadIdx.x >> 6;
    const int h = threadIdx.x & 63;
    const float* W = isUI ? Wui : Wsoc;
    float wreg[N_HID];
#pragma unroll
    for (int k = 0; k < N_HID; ++k) wreg[k] = W[k * N_HID + h];

    int r0 = rbeg + w * 16;
    int r1 = min(r0 + 16, rbeg + rlim);
    for (int row = r0; row < r1; ++row) {
        const float* src;
        float* op; size_t orow;
        if (isUI) {
            src = (row < N_USER) ? u + (size_t)row * N_HID
                                 : it + (size_t)(row - N_USER) * N_HID;
            op = out_ui; orow = row;
        } else {
            src = u + (size_t)(row - N_NODES) * N_HID;
            op = out_s; orow = row - N_NODES;
        }
        float x = src[h];
        op[orow * N_HID + h] = x;
        sm[w][h] = x;
        asm volatile("s_waitcnt lgkmcnt(0)" ::: "memory");
        float bacc = 0.f;
#pragma unroll
        for (int k = 0; k < N_HID; k += 4) {
            float4 x4 = *(const float4*)&sm[w][k];
            bacc = fmaf(x4.x, wreg[k],   bacc);
            bacc = fmaf(x4.y, wreg[k+1], bacc);
            bacc = fmaf(x4.z, wreg[k+2], bacc);
            bacc = fmaf(x4.w, wreg[k+3], bacc);
        }
        B[(size_t)row * N_HID + h] = bacc;
    }
}

// ===========================================================================
// spmm_q: quarter-wave (16 lanes, float4/lane) per destination row, batch-8
// ===========================================================================
template <bool FUSE>
__global__ __launch_bounds__(256) void spmm_q(const ull* __restrict__ pairs,
                                              const int* __restrict__ rowStart,
                                              const float* __restrict__ X,
                                              const float* __restrict__ Wui,
                                              const float* __restrict__ Wsoc,
                                              float* __restrict__ Bout,
                                              float* __restrict__ out_ui,
                                              float* __restrict__ out_s,
                                              int uiRows, int uiBlocks, int sRows) {
    __shared__ float Wsm[FUSE ? (N_HID * N_HID) : 4];
    __shared__ float smX[4][4 * SMSTR];
    const int tid = threadIdx.x;
    const bool isUI = (int)blockIdx.x < uiBlocks;
    const int bl    = isUI ? blockIdx.x : blockIdx.x - uiBlocks;
    const int rbeg  = isUI ? bl * BR : N_NODES + bl * BR;
    const int rlim  = isUI ? min(BR, uiRows - bl * BR) : min(BR, sRows - bl * BR);

    if (FUSE) {
        const float* W2 = isUI ? Wui : Wsoc;
#pragma unroll
        for (int c = 0; c < 4; ++c)
            *(float4*)&Wsm[c * 1024 + tid * 4] = *(const float4*)&W2[c * 1024 + tid * 4];
        __syncthreads();
    }

    const int w  = tid >> 6;
    const int q  = (tid >> 4) & 3;
    const int l4 = (tid & 15) * 4;
    float* smx = &smX[w][q * SMSTR];

    for (int i = 0; i < 4; ++i) {
        int row = rbeg + w * 16 + i * 4 + q;
        if (row >= rbeg + rlim) break;
        int s = rowStart[row];
        int e = rowStart[row + 1];
        float4 acc = make_float4(0.f, 0.f, 0.f, 0.f);
        for (int j = s; j < e; j += 8) {
            int last = e - 1;
            ull p[8]; float4 g[8]; float vv[8];
#pragma unroll
            for (int k = 0; k < 8; ++k) p[k] = pairs[min(j + k, last)];
#pragma unroll
            for (int k = 0; k < 8; ++k)
                g[k] = *(const float4*)(X + ((unsigned)p[k] * (unsigned)N_HID + l4));
#pragma unroll
            for (int k = 0; k < 8; ++k)
                vv[k] = (j + k < e) ? __uint_as_float((unsigned)(p[k] >> 32)) : 0.f;
#pragma unroll
            for (int k = 0; k < 8; ++k) {
                acc.x = fmaf(vv[k], g[k].x, acc.x);
                acc.y = fmaf(vv[k], g[k].y, acc.y);
                acc.z = fmaf(vv[k], g[k].z, acc.z);
                acc.w = fmaf(vv[k], g[k].w, acc.w);
            }
        }
        float4 lv;
        lv.x = (acc.x >= 0.f) ? acc.x : 0.5f * acc.x;
        lv.y = (acc.y >= 0.f) ? acc.y : 0.5f * acc.y;
        lv.z = (acc.z >= 0.f) ? acc.z : 0.5f * acc.z;
        lv.w = (acc.w >= 0.f) ? acc.w : 0.5f * acc.w;
        float ss = lv.x * lv.x + lv.y * lv.y + lv.z * lv.z + lv.w * lv.w;
        ss += __shfl_xor(ss, 1, 64);
        ss += __shfl_xor(ss, 2, 64);
        ss += __shfl_xor(ss, 4, 64);
        ss += __shfl_xor(ss, 8, 64);
        float inv = 1.f / fmaxf(sqrtf(ss), 1e-12f);

        float* op = isUI ? out_ui + (size_t)row * N_HID
                         : out_s  + (size_t)(row - N_NODES) * N_HID;
        float4 o = *(float4*)&op[l4];
        o.x = fmaf(lv.x, inv, o.x); o.y = fmaf(lv.y, inv, o.y);
        o.z = fmaf(lv.z, inv, o.z); o.w = fmaf(lv.w, inv, o.w);
        *(float4*)&op[l4] = o;

        if (FUSE) {
            *(float4*)&smx[l4] = lv;
            asm volatile("s_waitcnt lgkmcnt(0)" ::: "memory");
            float4 b = make_float4(0.f, 0.f, 0.f, 0.f);
#pragma unroll
            for (int k4 = 0; k4 < 16; ++k4) {
                float4 x4 = *(const float4*)&smx[k4 * 4];
                const float* wr = &Wsm[(k4 * 4) * N_HID + l4];
                float4 w0 = *(const float4*)(wr);
                float4 w1 = *(const float4*)(wr + N_HID);
                float4 w2 = *(const float4*)(wr + 2 * N_HID);
                float4 w3 = *(const float4*)(wr + 3 * N_HID);
                b.x = fmaf(x4.x, w0.x, b.x); b.x = fmaf(x4.y, w1.x, b.x);
                b.x = fmaf(x4.z, w2.x, b.x); b.x = fmaf(x4.w, w3.x, b.x);
                b.y = fmaf(x4.x, w0.y, b.y); b.y = fmaf(x4.y, w1.y, b.y);
                b.y = fmaf(x4.z, w2.y, b.y); b.y = fmaf(x4.w, w3.y, b.y);
                b.z = fmaf(x4.x, w0.z, b.z); b.z = fmaf(x4.y, w1.z, b.z);
                b.z = fmaf(x4.z, w2.z, b.z); b.z = fmaf(x4.w, w3.z, b.z);
                b.w = fmaf(x4.x, w0.w, b.w); b.w = fmaf(x4.y, w1.w, b.w);
                b.w = fmaf(x4.z, w2.w, b.w); b.w = fmaf(x4.w, w3.w, b.w);
            }
            *(float4*)&Bout[(size_t)row * N_HID + l4] = b;
        }
    }
}

// ===========================================================================
// Atomic fallback (only if ws too small for the sorted path)
// ===========================================================================
__global__ __launch_bounds__(256) void init_concat(const float* __restrict__ u,
                                                   const float* __restrict__ it,
                                                   float* __restrict__ A,
                                                   float* __restrict__ out) {
    int i = blockIdx.x * 256 + threadIdx.x;
    const int nu4 = N_USER * N_HID / 4;
    const int nt4 = N_NODES * N_HID / 4;
    if (i >= nt4) return;
    float4 v = (i < nu4) ? ((const float4*)u)[i] : ((const float4*)it)[i - nu4];
    ((float4*)A)[i]   = v;
    ((float4*)out)[i] = v;
}

__global__ __launch_bounds__(256) void copy2(const float* __restrict__ src,
                                             float* __restrict__ d0,
                                             float* __restrict__ d1, int n4) {
    int i = blockIdx.x * 256 + threadIdx.x;
    if (i >= n4) return;
    float4 v = ((const float4*)src)[i];
    ((float4*)d0)[i] = v;
    ((float4*)d1)[i] = v;
}

__global__ __launch_bounds__(256) void gemm64(const float* __restrict__ X,
                                              const float* __restrict__ W,
                                              float* __restrict__ Y, int nrows) {
    __shared__ float Ws[N_HID * N_HID];
    int tid = threadIdx.x;
#pragma unroll
    for (int c = 0; c < 16; ++c) Ws[c * 256 + tid] = W[c * 256 + tid];
    __syncthreads();
    int row = blockIdx.x * 256 + tid;
    if (row >= nrows) return;
    float x[N_HID];
    const float4* xr = (const float4*)(X + (size_t)row * N_HID);
#pragma unroll
    for (int c = 0; c < 16; ++c) {
        float4 v = xr[c];
        x[4*c+0] = v.x; x[4*c+1] = v.y; x[4*c+2] = v.z; x[4*c+3] = v.w;
    }
    float4* y4 = (float4*)(Y + (size_t)row * N_HID);
    for (int jc = 0; jc < 16; ++jc) {
        float4 a = make_float4(0.f,0.f,0.f,0.f);
#pragma unroll
        for (int k = 0; k < N_HID; ++k) {
            float4 wv = *((const float4*)&Ws[k * N_HID + jc * 4]);
            a.x += x[k]*wv.x; a.y += x[k]*wv.y; a.z += x[k]*wv.z; a.w += x[k]*wv.w;
        }
        y4[jc] = a;
    }
}

__global__ __launch_bounds__(256) void spmm_scatter(const int* __restrict__ rows,
                                                    const int* __restrict__ cols,
                                                    const float* __restrict__ vals,
                                                    const float* __restrict__ X,
                                                    float* __restrict__ Y, int nedges) {
    long long t = (long long)blockIdx.x * 256 + threadIdx.x;
    int e = (int)(t >> 6);
    int h = (int)(t & 63);
    if (e >= nedges) return;
    atomicAdd(&Y[rows[e] * N_HID + h], vals[e] * X[cols[e] * N_HID + h]);
}

__global__ __launch_bounds__(256) void leaky_norm_acc(float* __restrict__ Y,
                                                      float* __restrict__ out, int nrows) {
    int row = blockIdx.x * 4 + (threadIdx.x >> 6);
    int h   = threadIdx.x & 63;
    if (row >= nrows) return;
    int idx = row * N_HID + h;
    float v = Y[idx];
    v = (v >= 0.f) ? v : 0.5f * v;
    Y[idx] = v;
    float s = v * v;
#pragma unroll
    for (int off = 32; off > 0; off >>= 1) s += __shfl_xor(s, off, 64);
    out[idx] += v / fmaxf(sqrtf(s), 1e-12f);
}

// ===========================================================================
extern "C" void kernel_launch(void* const* d_in, const int* in_sizes, int n_in,
                              void* d_out, int out_size, void* d_ws, size_t ws_size,
                              hipStream_t stream) {
    const float* user_emb = (const float*)d_in[0];
    const float* item_emb = (const float*)d_in[1];
    const float* ui_w     = (const float*)d_in[2];
    const float* s_w      = (const float*)d_in[3];
    const int*   ui_rows  = (const int*)d_in[4];
    const int*   ui_cols  = (const int*)d_in[5];
    const float* ui_vals  = (const float*)d_in[6];
    const int*   s_rows   = (const int*)d_in[7];
    const int*   s_cols   = (const int*)d_in[8];
    const float* s_vals   = (const float*)d_in[9];

    float* out_ui = (float*)d_out;
    float* out_s  = (float*)d_out + (size_t)N_NODES * N_HID;

    const size_t szUI  = (size_t)N_NODES * N_HID * sizeof(float);   // 64.0 MB
    const size_t szTOT = (size_t)N_TOT   * N_HID * sizeof(float);   // 89.6 MB
    const size_t rsPad = 1400832;                                   // (N_TOT+1)*4 padded

    const int uiBlocks = (N_NODES + BR - 1) / BR;    // 3907
    const int sBlocks  = (N_USER  + BR - 1) / BR;    // 1563
    const int nbScan   = (N_TOT + 511) / 512;
    const int nbE      = (E_TOT + 255) / 256;
    const int nbP1     = (E_TOT + CH - 1) / CH;      // 489

    const size_t mergedNeed = 2 * szTOT + (size_t)E_TOT * 8 + rsPad + 8192 + 4096;
    const size_t branchNeed = 2 * szUI  + (size_t)E_TOT * 8 + rsPad + 8192 + 4096;

    if (ws_size >= branchNeed) {
        const bool merged = (ws_size >= mergedNeed);
        const size_t bsz  = merged ? szTOT : szUI;
        float* B1 = (float*)d_ws;
        float* B2 = (float*)((char*)d_ws + bsz);
        char*  p  = (char*)d_ws + 2 * bsz;
        ull* pairs     = (ull*)p;            p += (size_t)E_TOT * 8;
        int* rowStart  = (int*)p;            p += rsPad;
        int* blockSums = (int*)p;            p += 8192;
        int* bucketCur = (int*)p;
        ull* pairsA    = (ull*)B2;           // staging aliases B2 (dead until spmm1)

        // ---- sort: hist -> scan -> LDS-binned coarse scatter -> L2-local fine scatter
        hipMemsetAsync(rowStart, 0, (size_t)N_TOT * 4, stream);
        edge_hist2<<<nbE, 256, 0, stream>>>(ui_rows, s_rows, rowStart);
        scan_block512<<<nbScan, 256, 0, stream>>>(rowStart, blockSums, N_TOT);
        scan_sums<<<1, 1024, 0, stream>>>(blockSums, nbScan);
        scan_add512<<<nbScan, 256, 0, stream>>>(rowStart, blockSums, bucketCur, N_TOT, E_TOT);
        bin_pass1<<<nbP1, 256, 0, stream>>>(ui_rows, ui_cols, ui_vals,
                                            s_rows, s_cols, s_vals, bucketCur, pairsA);
        fine_pass2<<<NBKT, 256, 0, stream>>>(pairsA, rowStart, pairs);

        const float* Wui2 = ui_w + N_HID * N_HID;
        const float* Ws2  = s_w  + N_HID * N_HID;
        const size_t socOff = (size_t)N_NODES * N_HID;

        if (merged) {
            const int grid = uiBlocks + sBlocks;
            gemm_init_m<<<grid, 256, 0, stream>>>(user_emb, item_emb, ui_w, s_w,
                                                  B1, out_ui, out_s,
                                                  N_NODES, uiBlocks, N_USER);
            spmm_q<true><<<grid, 256, 0, stream>>>(pairs, rowStart, B1, Wui2, Ws2,
                                                   B2, out_ui, out_s,
                                                   N_NODES, uiBlocks, N_USER);
            spmm_q<false><<<grid, 256, 0, stream>>>(pairs, rowStart, B2, nullptr, nullptr,
                                                    B1, out_ui, out_s,
                                                    N_NODES, uiBlocks, N_USER);
        } else {
            float* B1s = (float*)((char*)B1 - socOff * sizeof(float));
            float* B2s = (float*)((char*)B2 - socOff * sizeof(float));
            gemm_init_m<<<uiBlocks, 256, 0, stream>>>(user_emb, item_emb, ui_w, s_w,
                                                      B1, out_ui, out_s,
                                                      N_NODES, uiBlocks, 0);
            spmm_q<true><<<uiBlocks, 256, 0, stream>>>(pairs, rowStart, B1, Wui2, Ws2,
                                                       B2, out_ui, out_s,
                                                       N_NODES, uiBlocks, 0);
            spmm_q<false><<<uiBlocks, 256, 0, stream>>>(pairs, rowStart, B2, nullptr, nullptr,
                                                        B1, out_ui, out_s,
                                                        N_NODES, uiBlocks, 0);
            gemm_init_m<<<sBlocks, 256, 0, stream>>>(user_emb, item_emb, ui_w, s_w,
                                                     B1s, out_ui, out_s,
                                                     0, 0, N_USER);
            spmm_q<true><<<sBlocks, 256, 0, stream>>>(pairs, rowStart, B1s, Wui2, Ws2,
                                                      B2s, out_ui, out_s,
                                                      0, 0, N_USER);
            spmm_q<false><<<sBlocks, 256, 0, stream>>>(pairs, rowStart, B2s, nullptr, nullptr,
                                                       B1s, out_ui, out_s,
                                                       0, 0, N_USER);
        }
        return;
    }

    // ------------------- fallback: atomic path -------------------
    float* A = (float*)d_ws;
    float* B = (float*)((char*)d_ws + szUI);
    init_concat<<<(N_NODES * N_HID / 4 + 255) / 256, 256, 0, stream>>>(
        user_emb, item_emb, A, out_ui);
    for (int l = 0; l < 2; ++l) {
        gemm64<<<(N_NODES + 255) / 256, 256, 0, stream>>>(
            A, ui_w + l * N_HID * N_HID, B, N_NODES);
        hipMemsetAsync(A, 0, szUI, stream);
        spmm_scatter<<<(int)(((long long)E_UI * 64) / 256), 256, 0, stream>>>(
            ui_rows, ui_cols, ui_vals, B, A, E_UI);
        leaky_norm_acc<<<(N_NODES + 3) / 4, 256, 0, stream>>>(A, out_ui, N_NODES);
    }
    copy2<<<(N_USER * N_HID / 4 + 255) / 256, 256, 0, stream>>>(
        user_emb, A, out_s, N_USER * N_HID / 4);
    const size_t sBytes = (size_t)N_USER * N_HID * sizeof(float);
    for (int l = 0; l < 2; ++l) {
        gemm64<<<(N_USER + 255) / 256, 256, 0, stream>>>(
            A, s_w + l * N_HID * N_HID, B, N_USER);
        hipMemsetAsync(A, 0, sBytes, stream);
        spmm_scatter<<<(int)(((long long)E_S * 64) / 256), 256, 0, stream>>>(
            s_rows, s_cols, s_vals, B, A, E_S);
        leaky_norm_acc<<<(N_USER + 3) / 4, 256, 0, stream>>>(A, out_s, N_USER);
    }
}